// Round 4
// baseline (164.541 us; speedup 1.0000x reference)
//
#include <hip/hip_runtime.h>

#define DIM 256
#define NHEADS 8
#define HDIM 32

typedef _Float16 half8_t __attribute__((ext_vector_type(8)));
typedef _Float16 half4_t __attribute__((ext_vector_type(4)));
typedef float float4_t __attribute__((ext_vector_type(4)));

// ---------------------------------------------------------------------------
// prep: (a) x fp32 -> fp16 flat; (b) Wqkv [256,768] -> WqT [768,256] fp16;
//       (c) Wout [256,256] -> WoT [256,256] fp16 (transposed for B-frags).
// ---------------------------------------------------------------------------
__global__ __launch_bounds__(256) void prep(const float* __restrict__ x,
                                            const float* __restrict__ Wqkv,
                                            const float* __restrict__ Wout,
                                            _Float16* __restrict__ xh,
                                            _Float16* __restrict__ WqT,
                                            _Float16* __restrict__ WoT) {
    __shared__ float ts[32][33];
    const int bid = blockIdx.x, t = threadIdx.x;
    if (bid < 1024) {
        size_t idx = (size_t)bid * 2048 + (size_t)t * 8;
        float tmp[8];
        *reinterpret_cast<float4*>(tmp)     = *reinterpret_cast<const float4*>(x + idx);
        *reinterpret_cast<float4*>(tmp + 4) = *reinterpret_cast<const float4*>(x + idx + 4);
        half8_t h;
        #pragma unroll
        for (int j = 0; j < 8; ++j) h[j] = (_Float16)tmp[j];
        *reinterpret_cast<half8_t*>(xh + idx) = h;
    } else {
        const float* src; _Float16* dst; int K, N, kb, nb;
        if (bid < 1024 + 192) { int b2 = bid - 1024; src = Wqkv; dst = WqT; K = 256; N = 768; nb = b2 % 24; kb = b2 / 24; }
        else                  { int b3 = bid - 1216; src = Wout; dst = WoT; K = 256; N = 256; nb = b3 % 8;  kb = b3 / 8; }
        const int tx = t & 31, ty = t >> 5;
        #pragma unroll
        for (int i = 0; i < 4; ++i) {
            int k = kb * 32 + ty + i * 8;
            ts[ty + i * 8][tx] = src[(size_t)k * N + nb * 32 + tx];
        }
        __syncthreads();
        #pragma unroll
        for (int i = 0; i < 4; ++i) {
            int nl = ty + i * 8;
            dst[(size_t)(nb * 32 + nl) * K + kb * 32 + tx] = (_Float16)ts[tx][nl];
        }
    }
}

// ---------------------------------------------------------------------------
// LDS-free fp16 MFMA GEMM: C[M,N] = A[M,K] @ BT[N,K]^T (+bias).
// 64x64 tile, 4 waves (each a 32x32 quadrant, 2x2 16x16x32 MFMAs per k-step).
// All fragments are direct-global half8 loads (16 B/lane); no LDS, no barriers.
// VSPLIT (gemm1 only): n-blocks with n0>=512 are the V part of QKV; they are
// written TRANSPOSED to VT[b][h][hd][n] (b64 stores), not to C.
// ---------------------------------------------------------------------------
template <bool OUT_HALF, bool VSPLIT>
__global__ __launch_bounds__(256) void gemm_g(const _Float16* __restrict__ A,
                                              const _Float16* __restrict__ BT,
                                              const float* __restrict__ bias,
                                              void* __restrict__ Cv,
                                              _Float16* __restrict__ VT,
                                              int M, int N, int K, int ldc) {
    const int t = threadIdx.x, lane = t & 63;
    const int wave = t >> 6;
    const int l16 = lane & 15, quad = lane >> 4;
    const int m0 = blockIdx.y * 64, n0 = blockIdx.x * 64;
    const int wr = (wave >> 1) * 32, wc = (wave & 1) * 32;

    float4_t acc[2][2];
    #pragma unroll
    for (int i = 0; i < 2; ++i)
        #pragma unroll
        for (int j = 0; j < 2; ++j) acc[i][j] = (float4_t){0.f, 0.f, 0.f, 0.f};

    const _Float16* ap0 = A  + (size_t)(m0 + wr + l16) * K + quad * 8;
    const _Float16* ap1 = ap0 + (size_t)16 * K;
    const _Float16* bp0 = BT + (size_t)(n0 + wc + l16) * K + quad * 8;
    const _Float16* bp1 = bp0 + (size_t)16 * K;

    #pragma unroll 4
    for (int k0 = 0; k0 < K; k0 += 32) {
        half8_t a0 = *reinterpret_cast<const half8_t*>(ap0 + k0);
        half8_t a1 = *reinterpret_cast<const half8_t*>(ap1 + k0);
        half8_t b0 = *reinterpret_cast<const half8_t*>(bp0 + k0);
        half8_t b1 = *reinterpret_cast<const half8_t*>(bp1 + k0);
        acc[0][0] = __builtin_amdgcn_mfma_f32_16x16x32_f16(a0, b0, acc[0][0], 0, 0, 0);
        acc[0][1] = __builtin_amdgcn_mfma_f32_16x16x32_f16(a0, b1, acc[0][1], 0, 0, 0);
        acc[1][0] = __builtin_amdgcn_mfma_f32_16x16x32_f16(a1, b0, acc[1][0], 0, 0, 0);
        acc[1][1] = __builtin_amdgcn_mfma_f32_16x16x32_f16(a1, b1, acc[1][1], 0, 0, 0);
    }

    if (VSPLIT && n0 >= 512) {
        // V part: write transposed VT[b][h][hd][token], 4 tokens per b64 store.
        const int bb = m0 >> 11;
        const int tok0 = (m0 & 2047) + wr;
        #pragma unroll
        for (int i = 0; i < 2; ++i)
            #pragma unroll
            for (int j = 0; j < 2; ++j) {
                int vcol = n0 + wc + j * 16 + l16 - 512;
                int hh = vcol >> 5, d = vcol & 31;
                half4_t p;
                #pragma unroll
                for (int r = 0; r < 4; ++r) p[r] = (_Float16)acc[i][j][r];
                *reinterpret_cast<half4_t*>(
                    VT + ((size_t)(bb * NHEADS + hh) * HDIM + d) * 2048
                       + tok0 + i * 16 + quad * 4) = p;
            }
    } else {
        #pragma unroll
        for (int i = 0; i < 2; ++i)
            #pragma unroll
            for (int r = 0; r < 4; ++r) {
                int row = m0 + wr + i * 16 + quad * 4 + r;
                #pragma unroll
                for (int j = 0; j < 2; ++j) {
                    int col = n0 + wc + j * 16 + l16;
                    float v = acc[i][j][r] + (bias ? bias[col] : 0.f);
                    if (OUT_HALF) ((_Float16*)Cv)[(size_t)row * ldc + col] = (_Float16)v;
                    else          ((float*)Cv)[(size_t)row * ldc + col] = v;
                }
            }
    }
}

// ---------------------------------------------------------------------------
// MFMA flash attention v3 (unnormalized exp, matches KeOps reference).
// Grid: 512 blocks = (b,h) x 16 q-blocks of 128; 4 waves, each owns 32 q
// (2 groups of 16). Zero barriers, no K/V LDS staging:
//   - Q, K fragments: direct-global half8 loads from qkh [8192][512].
//   - S^T = mfma(kf, qf): D holds S^T[key=quad*4+r][q=l16] -> E write is a
//     contiguous half4 (ds_write_b64) into per-wave es[32][40] (one 32-k
//     chunk live at a time; in-wave LDS ordering makes it race-free).
//   - E A-frags: ds_read_b128 from es; V B-frags: direct-global from
//     VT[b][h][hd][n] (written transposed by gemm1).
//   - denom accumulated per-lane from S^T layout, reduced with 2 shfl_xor.
// ---------------------------------------------------------------------------
__global__ __launch_bounds__(256) void attn_v3(const _Float16* __restrict__ qkh,
                                               const _Float16* __restrict__ VT,
                                               _Float16* __restrict__ outp) {
    __shared__ alignas(16) _Float16 es[4][32][40];
    const int bid = blockIdx.x;
    const int qb = bid & 15, bh = bid >> 4;
    const int b = bh >> 3, h = bh & 7;
    const int t = threadIdx.x, lane = t & 63, wave = t >> 6;
    const int l16 = lane & 15, quad = lane >> 4;
    const float scale = 0.17677669529663687f;  // 32^-0.5
    const int bN = b * 2048;
    const int q0w = qb * 128 + wave * 32;

    // Q fragments (B-operand of S^T), live in registers for the whole pass.
    const _Float16* qrow = qkh + (size_t)(bN + q0w + l16) * 512 + h * HDIM + quad * 8;
    half8_t qf0 = *reinterpret_cast<const half8_t*>(qrow);
    half8_t qf1 = *reinterpret_cast<const half8_t*>(qrow + (size_t)16 * 512);

    const _Float16* kbase = qkh + (size_t)(bN + l16) * 512 + 256 + h * HDIM + quad * 8;
    const _Float16* vbase = VT + (size_t)bh * HDIM * 2048 + (size_t)l16 * 2048 + quad * 8;

    float4_t num[2][2];
    #pragma unroll
    for (int g = 0; g < 2; ++g)
        #pragma unroll
        for (int dt = 0; dt < 2; ++dt) num[g][dt] = (float4_t){0.f, 0.f, 0.f, 0.f};
    float ds[2] = {0.f, 0.f};
    _Float16* esw = &es[wave][0][0];
    const float4_t z = {0.f, 0.f, 0.f, 0.f};

    for (int k0 = 0; k0 < 2048; k0 += 64) {
        // K fragments: 4 x 16 keys, direct global.
        const _Float16* kp = kbase + (size_t)k0 * 512;
        half8_t kf0 = *reinterpret_cast<const half8_t*>(kp);
        half8_t kf1 = *reinterpret_cast<const half8_t*>(kp + (size_t)16 * 512);
        half8_t kf2 = *reinterpret_cast<const half8_t*>(kp + (size_t)32 * 512);
        half8_t kf3 = *reinterpret_cast<const half8_t*>(kp + (size_t)48 * 512);

        // S^T = K Q^T : lane holds S^T[key=kb*16+quad*4+r][q=q0w+g*16+l16]
        float4_t st[4][2];
        st[0][0] = __builtin_amdgcn_mfma_f32_16x16x32_f16(kf0, qf0, z, 0, 0, 0);
        st[0][1] = __builtin_amdgcn_mfma_f32_16x16x32_f16(kf0, qf1, z, 0, 0, 0);
        st[1][0] = __builtin_amdgcn_mfma_f32_16x16x32_f16(kf1, qf0, z, 0, 0, 0);
        st[1][1] = __builtin_amdgcn_mfma_f32_16x16x32_f16(kf1, qf1, z, 0, 0, 0);
        st[2][0] = __builtin_amdgcn_mfma_f32_16x16x32_f16(kf2, qf0, z, 0, 0, 0);
        st[2][1] = __builtin_amdgcn_mfma_f32_16x16x32_f16(kf2, qf1, z, 0, 0, 0);
        st[3][0] = __builtin_amdgcn_mfma_f32_16x16x32_f16(kf3, qf0, z, 0, 0, 0);
        st[3][1] = __builtin_amdgcn_mfma_f32_16x16x32_f16(kf3, qf1, z, 0, 0, 0);

        // e = exp(s*scale); accumulate denom; pack to fp16 half4 per (kb,g).
        half4_t ep[4][2];
        #pragma unroll
        for (int kb = 0; kb < 4; ++kb)
            #pragma unroll
            for (int g = 0; g < 2; ++g)
                #pragma unroll
                for (int r = 0; r < 4; ++r) {
                    float e = __expf(st[kb][g][r] * scale);
                    ds[g] += e;
                    ep[kb][g][r] = (_Float16)e;
                }

        // Two 32-k chunks: E -> LDS (b64), E A-frag back (b128), PV MFMAs.
        #pragma unroll
        for (int s = 0; s < 2; ++s) {
            #pragma unroll
            for (int tt = 0; tt < 2; ++tt)
                #pragma unroll
                for (int g = 0; g < 2; ++g)
                    *reinterpret_cast<half4_t*>(
                        esw + (g * 16 + l16) * 40 + tt * 16 + quad * 4) = ep[s * 2 + tt][g];

            half8_t ef0 = *reinterpret_cast<const half8_t*>(esw + l16 * 40 + quad * 8);
            half8_t ef1 = *reinterpret_cast<const half8_t*>(esw + (16 + l16) * 40 + quad * 8);

            const _Float16* vp = vbase + k0 + s * 32;
            half8_t vf0 = *reinterpret_cast<const half8_t*>(vp);
            half8_t vf1 = *reinterpret_cast<const half8_t*>(vp + (size_t)16 * 2048);

            num[0][0] = __builtin_amdgcn_mfma_f32_16x16x32_f16(ef0, vf0, num[0][0], 0, 0, 0);
            num[0][1] = __builtin_amdgcn_mfma_f32_16x16x32_f16(ef0, vf1, num[0][1], 0, 0, 0);
            num[1][0] = __builtin_amdgcn_mfma_f32_16x16x32_f16(ef1, vf0, num[1][0], 0, 0, 0);
            num[1][1] = __builtin_amdgcn_mfma_f32_16x16x32_f16(ef1, vf1, num[1][1], 0, 0, 0);
        }
    }

    // denom: sum the 4 key-quads (columns complete per l16 after xor 16,32).
    #pragma unroll
    for (int g = 0; g < 2; ++g) {
        ds[g] += __shfl_xor(ds[g], 16, 64);
        ds[g] += __shfl_xor(ds[g], 32, 64);
    }

    // Scale + store: num D-layout holds rows q = g*16+quad*4+r, col d = dt*16+l16.
    _Float16* ob = outp + (size_t)(bN + q0w) * DIM + h * HDIM;
    #pragma unroll
    for (int g = 0; g < 2; ++g)
        #pragma unroll
        for (int r = 0; r < 4; ++r) {
            float rcp = 1.0f / (__shfl(ds[g], quad * 4 + r, 64) + 1e-6f);
            size_t ro = (size_t)(g * 16 + quad * 4 + r) * DIM;
            ob[ro + l16]      = (_Float16)(num[g][0][r] * rcp);
            ob[ro + 16 + l16] = (_Float16)(num[g][1][r] * rcp);
        }
}

extern "C" void kernel_launch(void* const* d_in, const int* in_sizes, int n_in,
                              void* d_out, int out_size, void* d_ws, size_t ws_size,
                              hipStream_t stream) {
    const float* x    = (const float*)d_in[0];
    const float* Wqkv = (const float*)d_in[1];
    const float* Wout = (const float*)d_in[2];
    const float* bout = (const float*)d_in[3];
    float* out = (float*)d_out;
    const int M = 8192;

    _Float16* xh    = (_Float16*)d_ws;                   // [8192,256]
    _Float16* WqT   = xh + (size_t)M * DIM;              // [768,256]
    _Float16* WoT   = WqT + 768 * 256;                   // [256,256]
    _Float16* qkh   = WoT + 256 * 256;                   // [8192,512]  (Q|K)
    _Float16* vt    = qkh + (size_t)M * 512;             // [4][8][32][2048] V^T
    _Float16* attnh = vt + (size_t)32 * HDIM * 2048;     // [8192,256]

    hipLaunchKernelGGL(prep, dim3(1280), dim3(256), 0, stream, x, Wqkv, Wout, xh, WqT, WoT);
    // qkv GEMM: Q,K -> qkh (ldc 512); V -> vt transposed.
    hipLaunchKernelGGL((gemm_g<true, true>), dim3(12, 128), dim3(256), 0, stream,
                       xh, WqT, (const float*)nullptr, (void*)qkh, vt, M, 768, DIM, 512);
    // attention
    hipLaunchKernelGGL(attn_v3, dim3(512), dim3(256), 0, stream, qkh, vt, attnh);
    // out = attn @ Wout + bout (fp32 out)
    hipLaunchKernelGGL((gemm_g<false, false>), dim3(4, 128), dim3(256), 0, stream,
                       attnh, WoT, bout, (void*)out, (_Float16*)nullptr, M, DIM, DIM, DIM);
}